// Round 1
// 196.413 us; speedup vs baseline: 1.0317x; 1.0317x over previous
//
#include <hip/hip_runtime.h>
#include <cstdint>
#include <cstddef>

// LSTM cell: B=4096, IN=1024, H=1024
//   ifgo = h @ Wh^T + bh + x @ Wx^T    [4096 x 4096]
//   i,f,g,o = split(ifgo); c' = sig(f)*c + sig(i)*tanh(g); h' = o*tanh(c')
//
// Pipeline (2 dispatches):
//   1. convert: fp32->bf16 into K=2048 layout (A_cat=[h|x], W_cat=[Wh|Wx])
//      with W rows permuted p=((j>>4)<<6)|(gate<<4)|(j&15) so each wave's 64
//      output columns hold all 4 gates of 16 consecutive j.  (unchanged)
//   2. gemm: 256x256 tile, BK=64, 8 waves, 8-phase schedule with counted
//      vmcnt (T3+T4), LDS XOR swizzle via pre-swizzled global source (T2),
//      s_setprio around MFMA clusters (T5), XCD-contiguous block swizzle (T1),
//      fused fast-math LSTM gate epilogue.

#define NB   4096
#define KH   1024
#define KK   2048
#define ARR_ELEMS 4194304  // 4096*1024
#define NKT  32            // K tiles of 64

typedef __bf16 bf16x8 __attribute__((ext_vector_type(8)));
typedef float  f32x4  __attribute__((ext_vector_type(4)));

__device__ inline unsigned short f2bf(float f) {
    union { float f; unsigned int u; } v; v.f = f;
    unsigned int u = v.u;
    u += 0x7FFFu + ((u >> 16) & 1u);   // RNE
    return (unsigned short)(u >> 16);
}

__device__ inline float fsig(float v)  { return __builtin_amdgcn_rcpf(1.f + __expf(-v)); }
__device__ inline float ftanh(float v) { return 1.f - 2.f * __builtin_amdgcn_rcpf(1.f + __expf(2.f * v)); }

// ---------------------------------------------------------------- convert ---
__global__ void convert_kernel(const float* __restrict__ h, const float* __restrict__ x,
                               const float* __restrict__ Wh, const float* __restrict__ Wx,
                               unsigned short* __restrict__ A, unsigned short* __restrict__ W) {
    int idx = blockIdx.x * 256 + threadIdx.x;
    int arr = idx >> 20;
    int off = (idx & 0xFFFFF) << 2;
    const float* src = (arr == 0) ? h : (arr == 1) ? x : (arr == 2) ? Wh : Wx;
    float4 v = *(const float4*)(src + off);
    unsigned int lo = (unsigned int)f2bf(v.x) | ((unsigned int)f2bf(v.y) << 16);
    unsigned int hi = (unsigned int)f2bf(v.z) | ((unsigned int)f2bf(v.w) << 16);
    uint2 packed; packed.x = lo; packed.y = hi;

    int row = off >> 10;
    int col = off & 1023;
    unsigned short* dst;
    size_t dstOff;
    if (arr < 2) {
        dst = A;
        dstOff = (size_t)row * KK + (arr == 1 ? 1024 : 0) + col;
    } else {
        int g = row >> 10, j = row & 1023;
        int p = ((j >> 4) << 6) | (g << 4) | (j & 15);
        dst = W;
        dstOff = (size_t)p * KK + (arr == 3 ? 1024 : 0) + col;
    }
    *(uint2*)(dst + dstOff) = packed;
}

// ------------------------------------------------------------------- gemm ---
// 512 threads = 8 waves (2 M-halves x 4 N-quarters). Wave output 128x64.
// LDS: 2 K-tile double buffer, [256 rows][64 k] bf16 per matrix per buffer,
// XOR-swizzled: phys_byte = row*128 + (kbyte ^ ((row&7)<<4)).  Staging keeps
// LDS linear (global_load_lds) and pre-swizzles the per-lane GLOBAL address
// (involution), so read-side swizzle sees correct data.
__global__ __launch_bounds__(512, 2) void gemm_kernel(const unsigned short* __restrict__ A,
                            const unsigned short* __restrict__ W,
                            const float* __restrict__ bh,
                            const float* __restrict__ c,
                            float* __restrict__ out) {
    __shared__ __align__(16) unsigned short As[2 * 16384];   // 64 KiB
    __shared__ __align__(16) unsigned short Bs[2 * 16384];   // 64 KiB

    const int tid  = threadIdx.x;
    const int wave = tid >> 6;
    const int lane = tid & 63;

    // T1: 256 blocks, 8 XCDs -> each XCD gets 32 contiguous tile-space ids
    const int bid   = (int)blockIdx.x;
    const int swz   = (bid & 7) * 32 + (bid >> 3);
    const int tileM = swz >> 4;        // 0..15
    const int tileN = swz & 15;        // 0..15

    const int wr  = wave >> 2;         // 0..1  M half
    const int wc  = wave & 3;          // 0..3  N quarter
    const int fr  = lane & 15;
    const int fk2 = (lane >> 4) << 4;  // fragment byte k-offset {0,16,32,48}

    // ---- staging: per-thread pre-swizzled global source pointers ----------
    // chunk c = i*512 + tid occupies LDS phys bytes [c*16, c*16+16); its
    // logical position is phys ^ swizzle (involution), mapped to global.
    const unsigned short* pa[4];
    const unsigned short* pb[4];
    #pragma unroll
    for (int i = 0; i < 4; ++i) {
        const int P   = (i * 512 + tid) * 16;
        const int L   = P ^ (((P >> 7) & 7) << 4);
        const int row = L >> 7;
        const int kk  = (L & 127) >> 1;
        pa[i] = A + (size_t)(tileM * 256 + row) * KK + kk;
        pb[i] = W + (size_t)(tileN * 256 + row) * KK + kk;
    }

    // ---- compute-side swizzled LDS byte offsets ---------------------------
    const int swzm = (fr & 7) << 4;
    int offA[8], offB[4];
    #pragma unroll
    for (int i = 0; i < 8; ++i)
        offA[i] = (wr * 128 + i * 16 + fr) * 128 + (fk2 ^ swzm);
    #pragma unroll
    for (int j = 0; j < 4; ++j)
        offB[j] = (wc * 64 + j * 16 + fr) * 128 + (fk2 ^ swzm);
    // second K=32 panel (s=1) toggles byte bit6: offset ^ 64 (mask covers bit6)

    f32x4 acc[8][4] = {};
    bf16x8 afr[4][2], bfr[4][2];

#define STAGE(KT, BUF) do { \
    const size_t _ko = (size_t)(KT) * 64; \
    _Pragma("unroll") \
    for (int _i = 0; _i < 4; ++_i) { \
        __builtin_amdgcn_global_load_lds( \
            (const __attribute__((address_space(1))) void*)(pa[_i] + _ko), \
            (__attribute__((address_space(3))) void*)(As + (BUF) * 16384 + _i * 4096 + wave * 512), 16, 0, 0); \
        __builtin_amdgcn_global_load_lds( \
            (const __attribute__((address_space(1))) void*)(pb[_i] + _ko), \
            (__attribute__((address_space(3))) void*)(Bs + (BUF) * 16384 + _i * 4096 + wave * 512), 16, 0, 0); \
    } \
} while (0)

#define MFMA16(IB, JB) do { \
    _Pragma("unroll") \
    for (int _i = 0; _i < 4; ++_i) \
        _Pragma("unroll") \
        for (int _j = 0; _j < 2; ++_j) \
            _Pragma("unroll") \
            for (int _s = 0; _s < 2; ++_s) \
                acc[(IB) + _i][(JB) + _j] = __builtin_amdgcn_mfma_f32_16x16x32_bf16( \
                    afr[_i][_s], bfr[(JB) + _j][_s], acc[(IB) + _i][(JB) + _j], 0, 0, 0); \
} while (0)

    // prologue: tiles 0,1 in flight; tile 0 guaranteed landed
    STAGE(0, 0);
    STAGE(1, 1);
    asm volatile("s_waitcnt vmcnt(8)" ::: "memory");
    asm volatile("s_barrier" ::: "memory");

// One K-tile = 4 phases.  Safety invariants:
//  - reads of buf happen after prev tile's vmcnt(8)+barrier (tile landed)
//  - STAGE into buf issued only after phase-3-end barrier (all waves done
//    reading buf; each wave's reads completed before its phase-3 lgkmcnt(0))
//  - vmcnt(8) at phase-4 end drains everything except the 8 just-issued loads
#define TILE(T, BUF) do { \
    const char* AsB = (const char*)As + (BUF) * 32768; \
    const char* BsB = (const char*)Bs + (BUF) * 32768; \
    /* phase 1: read a[m0-3] both k-halves + b[n0-1]; MFMA q(m0-3,n0-1) */ \
    _Pragma("unroll") \
    for (int i = 0; i < 4; ++i) { \
        afr[i][0] = *(const bf16x8*)(AsB + offA[i]); \
        afr[i][1] = *(const bf16x8*)(AsB + (offA[i] ^ 64)); \
    } \
    _Pragma("unroll") \
    for (int j = 0; j < 2; ++j) { \
        bfr[j][0] = *(const bf16x8*)(BsB + offB[j]); \
        bfr[j][1] = *(const bf16x8*)(BsB + (offB[j] ^ 64)); \
    } \
    asm volatile("s_barrier" ::: "memory"); \
    asm volatile("s_waitcnt lgkmcnt(0)" ::: "memory"); \
    __builtin_amdgcn_s_setprio(1); \
    MFMA16(0, 0); \
    __builtin_amdgcn_s_setprio(0); \
    asm volatile("s_barrier" ::: "memory"); \
    /* phase 2: read b[n2-3]; MFMA q(m0-3,n2-3) */ \
    _Pragma("unroll") \
    for (int j = 2; j < 4; ++j) { \
        bfr[j][0] = *(const bf16x8*)(BsB + offB[j]); \
        bfr[j][1] = *(const bf16x8*)(BsB + (offB[j] ^ 64)); \
    } \
    asm volatile("s_barrier" ::: "memory"); \
    asm volatile("s_waitcnt lgkmcnt(0)" ::: "memory"); \
    __builtin_amdgcn_s_setprio(1); \
    MFMA16(0, 2); \
    __builtin_amdgcn_s_setprio(0); \
    asm volatile("s_barrier" ::: "memory"); \
    /* phase 3: read a[m4-7] (reuse regs); MFMA q(m4-7,n0-1) */ \
    _Pragma("unroll") \
    for (int i = 0; i < 4; ++i) { \
        afr[i][0] = *(const bf16x8*)(AsB + offA[4 + i]); \
        afr[i][1] = *(const bf16x8*)(AsB + (offA[4 + i] ^ 64)); \
    } \
    asm volatile("s_barrier" ::: "memory"); \
    asm volatile("s_waitcnt lgkmcnt(0)" ::: "memory"); \
    __builtin_amdgcn_s_setprio(1); \
    MFMA16(4, 0); \
    __builtin_amdgcn_s_setprio(0); \
    asm volatile("s_barrier" ::: "memory"); \
    /* phase 4: stage tile T+2 (buf now free), MFMA q(m4-7,n2-3), vmcnt(8) */ \
    { \
        const int _ktc = ((T) + 2 <= NKT - 1) ? ((T) + 2) : (NKT - 1); \
        STAGE(_ktc, BUF); /* clamp keeps vmcnt counts uniform; writes only dead buffers */ \
    } \
    asm volatile("s_barrier" ::: "memory"); \
    __builtin_amdgcn_s_setprio(1); \
    MFMA16(4, 2); \
    __builtin_amdgcn_s_setprio(0); \
    asm volatile("s_waitcnt vmcnt(8)" ::: "memory"); \
    asm volatile("s_barrier" ::: "memory"); \
} while (0)

    for (int tt = 0; tt < NKT; tt += 2) {
        TILE(tt, 0);
        TILE(tt + 1, 1);
    }
#undef TILE
#undef MFMA16
#undef STAGE

    // ---- fused LSTM gate epilogue -----------------------------------------
    // acc[i][g][r]: row = tileM*256 + wr*128 + i*16 + (lane>>4)*4 + r,
    // col (permuted W space) -> gate g, logical j = (tileN*4+wc)*16 + (lane&15)
    const int j = ((tileN * 4 + wc) << 4) | fr;
    const float bi  = bh[j];
    const float bff = bh[j + 1024];
    const float bg  = bh[j + 2048];
    const float bo  = bh[j + 3072];

    const int row0 = tileM * 256 + wr * 128 + (lane >> 4) * 4;

    float cv[8][4];
    #pragma unroll
    for (int i = 0; i < 8; ++i)
        #pragma unroll
        for (int r = 0; r < 4; ++r)
            cv[i][r] = c[(size_t)(row0 + i * 16 + r) * KH + j];

    #pragma unroll
    for (int i = 0; i < 8; ++i) {
        #pragma unroll
        for (int r = 0; r < 4; ++r) {
            const size_t idx = (size_t)(row0 + i * 16 + r) * KH + j;
            float iv = fsig(acc[i][0][r] + bi);
            float fv = fsig(acc[i][1][r] + bff);
            float gv = ftanh(acc[i][2][r] + bg);
            float ov = fsig(acc[i][3][r] + bo);
            float cn = fv * cv[i][r] + iv * gv;
            float hn = ov * ftanh(cn);
            out[idx] = hn;
            out[(size_t)ARR_ELEMS + idx] = cn;
        }
    }
}

// ----------------------------------------------------------------- launch ---
extern "C" void kernel_launch(void* const* d_in, const int* in_sizes, int n_in,
                              void* d_out, int out_size, void* d_ws, size_t ws_size,
                              hipStream_t stream) {
    const float* x  = (const float*)d_in[0];
    const float* h  = (const float*)d_in[1];
    const float* c  = (const float*)d_in[2];
    const float* Wh = (const float*)d_in[3];
    const float* bh = (const float*)d_in[4];
    const float* Wx = (const float*)d_in[5];
    float* out = (float*)d_out;

    unsigned short* ws   = (unsigned short*)d_ws;
    unsigned short* Acat = ws;
    unsigned short* Wcat = ws + 2 * (size_t)ARR_ELEMS;

    convert_kernel<<<16384, 256, 0, stream>>>(h, x, Wh, Wx, Acat, Wcat);
    gemm_kernel<<<256, 512, 0, stream>>>(Acat, Wcat, bh, c, out);
}

// Round 2
// 194.770 us; speedup vs baseline: 1.0404x; 1.0084x over previous
//
#include <hip/hip_runtime.h>
#include <cstdint>
#include <cstddef>

// LSTM cell: B=4096, IN=1024, H=1024
//   ifgo = h @ Wh^T + bh + x @ Wx^T    [4096 x 4096]
//   i,f,g,o = split(ifgo); c' = sig(f)*c + sig(i)*tanh(g); h' = o*tanh(c')
//
// Pipeline (2 dispatches):
//   1. convert: fp32->bf16, 8 floats/thread (16B stores), K=2048 layout
//      (A_cat=[h|x], W_cat=[Wh|Wx]) with W rows permuted
//      p=((j>>4)<<6)|(gate<<4)|(j&15).
//   2. gemm: 256x256 tile, BK=64, 8 waves, MINIMUM-BARRIER schedule:
//      2 barriers per K-tile (not per phase), counted lgkmcnt via compiler,
//      vmcnt(8) never 0, quadrant-pipelined register fragments, LDS XOR
//      swizzle (conflicts=0 verified r1), XCD swizzle, setprio on MFMA,
//      fused fast-math LSTM gate epilogue.

#define NB   4096
#define KH   1024
#define KK   2048
#define ARR_ELEMS 4194304  // 4096*1024
#define NKT  32            // K tiles of 64

typedef __bf16 bf16x8 __attribute__((ext_vector_type(8)));
typedef float  f32x4  __attribute__((ext_vector_type(4)));

__device__ inline unsigned short f2bf(float f) {
    union { float f; unsigned int u; } v; v.f = f;
    unsigned int u = v.u;
    u += 0x7FFFu + ((u >> 16) & 1u);   // RNE
    return (unsigned short)(u >> 16);
}

__device__ inline float fsig(float v)  { return __builtin_amdgcn_rcpf(1.f + __expf(-v)); }
__device__ inline float ftanh(float v) { return 1.f - 2.f * __builtin_amdgcn_rcpf(1.f + __expf(2.f * v)); }

// ---------------------------------------------------------------- convert ---
// 8 floats per thread: 2x float4 load, 1x uint4 (16B) store.
__global__ void convert_kernel(const float* __restrict__ h, const float* __restrict__ x,
                               const float* __restrict__ Wh, const float* __restrict__ Wx,
                               unsigned short* __restrict__ A, unsigned short* __restrict__ W) {
    int idx = blockIdx.x * 256 + threadIdx.x;       // 0 .. 2M-1
    int arr = idx >> 19;                            // which source array
    int off = (idx & 0x7FFFF) << 3;                 // float offset within array
    const float* src = (arr == 0) ? h : (arr == 1) ? x : (arr == 2) ? Wh : Wx;
    float4 v0 = *(const float4*)(src + off);
    float4 v1 = *(const float4*)(src + off + 4);
    uint4 packed;
    packed.x = (unsigned int)f2bf(v0.x) | ((unsigned int)f2bf(v0.y) << 16);
    packed.y = (unsigned int)f2bf(v0.z) | ((unsigned int)f2bf(v0.w) << 16);
    packed.z = (unsigned int)f2bf(v1.x) | ((unsigned int)f2bf(v1.y) << 16);
    packed.w = (unsigned int)f2bf(v1.z) | ((unsigned int)f2bf(v1.w) << 16);

    int row = off >> 10;
    int col = off & 1023;
    unsigned short* dst;
    size_t dstOff;
    if (arr < 2) {                                  // A_cat: [h | x] per row
        dst = A;
        dstOff = (size_t)row * KK + (arr == 1 ? 1024 : 0) + col;
    } else {                                        // W_cat: permuted rows
        int g = row >> 10, j = row & 1023;
        int p = ((j >> 4) << 6) | (g << 4) | (j & 15);
        dst = W;
        dstOff = (size_t)p * KK + (arr == 3 ? 1024 : 0) + col;
    }
    *(uint4*)(dst + dstOff) = packed;
}

// ------------------------------------------------------------------- gemm ---
// 512 threads = 8 waves (2 M-halves x 4 N-quarters). Wave output 128x64.
// LDS: double-buffered K-tiles, [256 rows][64 k] bf16, XOR swizzle
// phys_byte = row*128 + (kbyte ^ ((row&7)<<4)); staging keeps LDS linear
// (global_load_lds) and pre-swizzles the per-lane GLOBAL address.
//
// Per K-tile schedule (2 barriers total):
//   read b01,a03 ; read a47 ; MFMA q1(a03,b01)   <- q1 waits lgkm(8), a47 hides
//   read b23     ; MFMA q2(a47,b01)              <- q2 waits lgkm(4)
//                  MFMA q3(a47,b23)
//   lgkm(0) ; barrier              <- all waves done reading buf b
//   STAGE(T+2 -> b)                <- write-after-read safe
//   vmcnt(8) ; barrier             <- tile T+1 (other buf) landed
//   MFMA q4(a03,b23)               <- register-only, hides clump neighborhood
__global__ __launch_bounds__(512, 2) void gemm_kernel(const unsigned short* __restrict__ A,
                            const unsigned short* __restrict__ W,
                            const float* __restrict__ bh,
                            const float* __restrict__ c,
                            float* __restrict__ out) {
    __shared__ __align__(16) unsigned short As[2 * 16384];   // 64 KiB
    __shared__ __align__(16) unsigned short Bs[2 * 16384];   // 64 KiB

    const int tid  = threadIdx.x;
    const int wave = tid >> 6;
    const int lane = tid & 63;

    // T1: 256 blocks, 8 XCDs -> contiguous 32-tile chunks per XCD
    const int bid   = (int)blockIdx.x;
    const int swz   = (bid & 7) * 32 + (bid >> 3);
    const int tileM = swz >> 4;        // 0..15
    const int tileN = swz & 15;        // 0..15

    const int wr  = wave >> 2;         // 0..1  M half
    const int wc  = wave & 3;          // 0..3  N quarter
    const int fr  = lane & 15;
    const int fk2 = (lane >> 4) << 4;  // fragment byte k-offset {0,16,32,48}

    // ---- staging: per-thread pre-swizzled global source pointers ----------
    const unsigned short* pa[4];
    const unsigned short* pb[4];
    #pragma unroll
    for (int i = 0; i < 4; ++i) {
        const int P   = (i * 512 + tid) * 16;
        const int L   = P ^ (((P >> 7) & 7) << 4);
        const int row = L >> 7;
        const int kk  = (L & 127) >> 1;
        pa[i] = A + (size_t)(tileM * 256 + row) * KK + kk;
        pb[i] = W + (size_t)(tileN * 256 + row) * KK + kk;
    }

    // ---- compute-side swizzled LDS byte offsets ---------------------------
    const int swzm = (fr & 7) << 4;
    int offA[8], offB[4];
    #pragma unroll
    for (int i = 0; i < 8; ++i)
        offA[i] = (wr * 128 + i * 16 + fr) * 128 + (fk2 ^ swzm);
    #pragma unroll
    for (int j = 0; j < 4; ++j)
        offB[j] = (wc * 64 + j * 16 + fr) * 128 + (fk2 ^ swzm);
    // second K=32 panel (s=1): offset ^ 64

    f32x4 acc[8][4] = {};
    bf16x8 a03[4][2], a47[4][2], b01[2][2], b23[2][2];

#define STAGE(KT, BUF) do { \
    const size_t _ko = (size_t)(KT) * 64; \
    _Pragma("unroll") \
    for (int _i = 0; _i < 4; ++_i) { \
        __builtin_amdgcn_global_load_lds( \
            (const __attribute__((address_space(1))) void*)(pa[_i] + _ko), \
            (__attribute__((address_space(3))) void*)(As + (BUF) * 16384 + _i * 4096 + wave * 512), 16, 0, 0); \
        __builtin_amdgcn_global_load_lds( \
            (const __attribute__((address_space(1))) void*)(pb[_i] + _ko), \
            (__attribute__((address_space(3))) void*)(Bs + (BUF) * 16384 + _i * 4096 + wave * 512), 16, 0, 0); \
    } \
} while (0)

#define READ_A(dst, base, AsB) do { \
    _Pragma("unroll") \
    for (int _i = 0; _i < 4; ++_i) { \
        dst[_i][0] = *(const bf16x8*)((AsB) + offA[(base) + _i]); \
        dst[_i][1] = *(const bf16x8*)((AsB) + (offA[(base) + _i] ^ 64)); \
    } \
} while (0)

#define READ_B(dst, base, BsB) do { \
    _Pragma("unroll") \
    for (int _j = 0; _j < 2; ++_j) { \
        dst[_j][0] = *(const bf16x8*)((BsB) + offB[(base) + _j]); \
        dst[_j][1] = *(const bf16x8*)((BsB) + (offB[(base) + _j] ^ 64)); \
    } \
} while (0)

#define MFMAQ(af, bf, IB, JB) do { \
    __builtin_amdgcn_s_setprio(1); \
    _Pragma("unroll") \
    for (int _i = 0; _i < 4; ++_i) \
        _Pragma("unroll") \
        for (int _j = 0; _j < 2; ++_j) \
            _Pragma("unroll") \
            for (int _s = 0; _s < 2; ++_s) \
                acc[(IB) + _i][(JB) + _j] = __builtin_amdgcn_mfma_f32_16x16x32_bf16( \
                    af[_i][_s], bf[_j][_s], acc[(IB) + _i][(JB) + _j], 0, 0, 0); \
    __builtin_amdgcn_s_setprio(0); \
} while (0)

// One K-tile.  Hazard invariants:
//  - tile T's data in buf was confirmed landed by tile T-1's vmcnt(8)+barrier
//  - q1..q3 issue ALL this tile's ds_reads; lgkm(0)+barrier -> buf dead
//  - STAGE(T+2 -> buf) only after that barrier (write-after-read safe)
//  - vmcnt(8) leaves only the 8 just-issued loads outstanding -> tile T+1
//    (other buf, issued one tile ago) has landed; barrier publishes it
//  - q4 uses registers only; next tile's reads cannot hoist above the
//    vmcnt+barrier ("memory" clobbers)
#define TILEBODY(T, BUF) do { \
    const char* AsB = (const char*)As + (BUF) * 32768; \
    const char* BsB = (const char*)Bs + (BUF) * 32768; \
    READ_B(b01, 0, BsB); \
    READ_A(a03, 0, AsB); \
    READ_A(a47, 4, AsB); \
    MFMAQ(a03, b01, 0, 0); \
    READ_B(b23, 2, BsB); \
    MFMAQ(a47, b01, 4, 0); \
    MFMAQ(a47, b23, 4, 2); \
    asm volatile("s_waitcnt lgkmcnt(0)" ::: "memory"); \
    asm volatile("s_barrier" ::: "memory"); \
    { \
        const int _kt = ((T) + 2 <= NKT - 1) ? ((T) + 2) : (NKT - 1); \
        STAGE(_kt, BUF);   /* clamp: tail writes target only dead buffers */ \
    } \
    asm volatile("s_waitcnt vmcnt(8)" ::: "memory"); \
    asm volatile("s_barrier" ::: "memory"); \
    MFMAQ(a03, b23, 0, 2); \
} while (0)

    // prologue: tiles 0,1 in flight; tile 0 guaranteed landed
    STAGE(0, 0);
    STAGE(1, 1);
    asm volatile("s_waitcnt vmcnt(8)" ::: "memory");
    asm volatile("s_barrier" ::: "memory");

    for (int tt = 0; tt < NKT; tt += 2) {
        TILEBODY(tt, 0);
        TILEBODY(tt + 1, 1);
    }
#undef TILEBODY
#undef MFMAQ
#undef READ_A
#undef READ_B
#undef STAGE

    // ---- fused LSTM gate epilogue -----------------------------------------
    // acc[i][g][r]: row = tileM*256 + wr*128 + i*16 + (lane>>4)*4 + r,
    // gate g, logical j = (tileN*4+wc)*16 + (lane&15)
    const int j = ((tileN * 4 + wc) << 4) | fr;
    const float bi  = bh[j];
    const float bff = bh[j + 1024];
    const float bg  = bh[j + 2048];
    const float bo  = bh[j + 3072];

    const int row0 = tileM * 256 + wr * 128 + (lane >> 4) * 4;

    float cv[8][4];
    #pragma unroll
    for (int i = 0; i < 8; ++i)
        #pragma unroll
        for (int r = 0; r < 4; ++r)
            cv[i][r] = c[(size_t)(row0 + i * 16 + r) * KH + j];

    #pragma unroll
    for (int i = 0; i < 8; ++i) {
        #pragma unroll
        for (int r = 0; r < 4; ++r) {
            const size_t idx = (size_t)(row0 + i * 16 + r) * KH + j;
            float iv = fsig(acc[i][0][r] + bi);
            float fv = fsig(acc[i][1][r] + bff);
            float gv = ftanh(acc[i][2][r] + bg);
            float ov = fsig(acc[i][3][r] + bo);
            float cn = fv * cv[i][r] + iv * gv;
            float hn = ov * ftanh(cn);
            out[idx] = hn;
            out[(size_t)ARR_ELEMS + idx] = cn;
        }
    }
}

// ----------------------------------------------------------------- launch ---
extern "C" void kernel_launch(void* const* d_in, const int* in_sizes, int n_in,
                              void* d_out, int out_size, void* d_ws, size_t ws_size,
                              hipStream_t stream) {
    const float* x  = (const float*)d_in[0];
    const float* h  = (const float*)d_in[1];
    const float* c  = (const float*)d_in[2];
    const float* Wh = (const float*)d_in[3];
    const float* bh = (const float*)d_in[4];
    const float* Wx = (const float*)d_in[5];
    float* out = (float*)d_out;

    unsigned short* ws   = (unsigned short*)d_ws;
    unsigned short* Acat = ws;
    unsigned short* Wcat = ws + 2 * (size_t)ARR_ELEMS;

    convert_kernel<<<8192, 256, 0, stream>>>(h, x, Wh, Wx, Acat, Wcat);
    gemm_kernel<<<256, 512, 0, stream>>>(Acat, Wcat, bh, c, out);
}